// Round 4
// baseline (9699.277 us; speedup 1.0000x reference)
//
#include <hip/hip_runtime.h>

#define LENSZ 11
#define RAD   5
#define TSX   64            // tile width  (4 px per thread in x)
#define TSY   16            // tile height
#define WINX  (TSX + LENSZ - 1)   // 74
#define WINY  (TSY + LENSZ - 1)   // 26
#define NI    19            // ceil(WINX/4)
#define WXP   76            // padded window width for staging (4*NI)
#define IMG_H 1024
#define IMG_W 1024
#define HW    (IMG_H * IMG_W)

// sigmoid(4*(sd-dd)) = 1/(1 + exp2(C4L2*(sd-dd))), C4L2 = -4*log2(e)
#define C4L2  (-5.770780163555854f)

typedef float v2f __attribute__((ext_vector_type(2)));

// compile-time sqrt (Newton), for the disk distance constants
constexpr double csqrt_(double x) {
    double g = x > 1.0 ? x : 1.0;
    for (int i = 0; i < 48; ++i) g = 0.5 * (g + (g > 0 ? x / g : 0.0));
    return g;
}
// c0 = 0.5 - dist; offsets outside the disk (dist > 5.5 <=> n > 30) get -1e30
// so clamp(coc + c0, 0, 1) == 0 -> weight 0. This also absorbs pair-edge cases.
constexpr float C0V(int dy, int dx) {
    int n = dy * dy + dx * dx;
    return (n <= 30) ? (float)(0.5 - csqrt_((double)n)) : -1e30f;
}

// One window row at runtime y-index `wy`, with compile-time |dy| and disk
// x-bounds. Dests j=0..3 processed as packed pairs {0,1},{2,3}.
template<int ADY, int XMN, int XMX>
__device__ __forceinline__ void do_row(
    const float4 (&w4)[4][WINY][NI], int wy, int tx, float scale,
    v2f G01, v2f G23,
    v2f& nr01, v2f& nr23, v2f& ng01, v2f& ng23,
    v2f& nb01, v2f& nb23, v2f& dn01, v2f& dn23)
{
#pragma unroll
    for (int kxp = XMN; kxp <= XMX + 3; ++kxp) {
        float4 s = w4[kxp & 3][wy][tx + (kxp >> 2)];
        const float sd  = s.w;
        const float coc = scale * fabsf(sd);
        const float Es  = __builtin_amdgcn_exp2f(fminf(C4L2 * sd, 63.f));
        const v2f Es2 = {Es, Es};
        const v2f coc2 = {coc, coc};
        const v2f sx2 = {s.x, s.x}, sy2 = {s.y, s.y}, sz2 = {s.z, s.z};

        if (kxp <= XMX + 1) {  // pair {j=0,1}: kx = kxp, kxp-1  (folds post-unroll)
            const v2f c0 = {C0V(ADY, kxp - RAD), C0V(ADY, kxp - 1 - RAD)};
            v2f t = coc2 + c0;                                    // pk_add
            v2f w0 = {fminf(fmaxf(t.x, 0.f), 1.f),
                      fminf(fmaxf(t.y, 0.f), 1.f)};               // med3 x2
            v2f f = Es2 * G01 + (v2f){1.f, 1.f};                  // pk_fma
            float r = __builtin_amdgcn_rcpf(f.x * f.y);
            v2f occ = {r * f.y, r * f.x};
            v2f w = w0 * occ;                                     // pk_mul
            nr01 = w * sx2 + nr01;                                // pk_fma
            ng01 = w * sy2 + ng01;
            nb01 = w * sz2 + nb01;
            dn01 = dn01 + w;                                      // pk_add
        }
        if (kxp >= XMN + 2) {  // pair {j=2,3}: kx = kxp-2, kxp-3
            const v2f c0 = {C0V(ADY, kxp - 2 - RAD), C0V(ADY, kxp - 3 - RAD)};
            v2f t = coc2 + c0;
            v2f w0 = {fminf(fmaxf(t.x, 0.f), 1.f),
                      fminf(fmaxf(t.y, 0.f), 1.f)};
            v2f f = Es2 * G23 + (v2f){1.f, 1.f};
            float r = __builtin_amdgcn_rcpf(f.x * f.y);
            v2f occ = {r * f.y, r * f.x};
            v2f w = w0 * occ;
            nr23 = w * sx2 + nr23;
            ng23 = w * sy2 + ng23;
            nb23 = w * sz2 + nb23;
            dn23 = dn23 + w;
        }
    }
}

__global__ __launch_bounds__(256) void scatter_render_kernel(
    const float* __restrict__ x,      // (B,4,H,W)
    const float* __restrict__ lens,   // (B,1)
    float* __restrict__ out)          // (B,3,H,W)
{
    // column-mod-4 interleaved window: element (wy, c) at win4[c&3][wy][c>>2]
    __shared__ float4 win4[4][WINY][NI];

    const int b   = blockIdx.z;
    const int bx0 = blockIdx.x * TSX;
    const int by0 = blockIdx.y * TSY;
    const int tx  = threadIdx.x;      // 0..15
    const int ty  = threadIdx.y;      // 0..15
    const int tid = ty * 16 + tx;

    const float scale = lens[b];
    const float* xb = x + (size_t)b * 4 * HW;

    // ---- stage window: coalesced global reads, bank-uniform LDS writes
    for (int idx = tid; idx < WINY * WXP; idx += 256) {
        int wy = idx / WXP;
        int c  = idx - wy * WXP;
        int cc = min(c, WINX - 1);               // clamp padding columns
        int gy = by0 - RAD + wy; gy = min(max(gy, 0), IMG_H - 1);
        int gx = bx0 - RAD + cc; gx = min(max(gx, 0), IMG_W - 1);
        int base = gy * IMG_W + gx;
        float4 v;
        v.x = xb[base];
        v.y = xb[base + HW];
        v.z = xb[base + 2 * HW];
        v.w = xb[base + 3 * HW];
        win4[c & 3][wy][c >> 2] = v;
    }
    __syncthreads();

    // per-dest occlusion gate: G_j = exp2(min(-C4L2 * dd_j, 63))
    float G[4];
#pragma unroll
    for (int j = 0; j < 4; ++j) {
        const int cc = 4 * tx + j + RAD;
        float dd = win4[cc & 3][ty + RAD][cc >> 2].w;
        G[j] = __builtin_amdgcn_exp2f(fminf(-C4L2 * dd, 63.f));
    }
    const v2f G01 = {G[0], G[1]}, G23 = {G[2], G[3]};

    v2f nr01 = {0,0}, nr23 = {0,0}, ng01 = {0,0}, ng23 = {0,0};
    v2f nb01 = {0,0}, nb23 = {0,0}, dn01 = {0,0}, dn23 = {0,0};

    // mirrored row pairs share |dy| -> c0 fully compile-time; runtime 2-trip
    // loops keep live ranges bounded (R1's full unroll spilled).
#pragma unroll 1
    for (int t = 0; t < 2; ++t)
        do_row<5, 3, 7>(win4, ty + t * 10, tx, scale, G01, G23,
                        nr01, nr23, ng01, ng23, nb01, nb23, dn01, dn23);
#pragma unroll 1
    for (int t = 0; t < 2; ++t)
        do_row<4, 2, 8>(win4, ty + 1 + t * 8, tx, scale, G01, G23,
                        nr01, nr23, ng01, ng23, nb01, nb23, dn01, dn23);
#pragma unroll 1
    for (int t = 0; t < 2; ++t)
        do_row<3, 1, 9>(win4, ty + 2 + t * 6, tx, scale, G01, G23,
                        nr01, nr23, ng01, ng23, nb01, nb23, dn01, dn23);
#pragma unroll 1
    for (int t = 0; t < 2; ++t)
        do_row<2, 0, 10>(win4, ty + 3 + t * 4, tx, scale, G01, G23,
                         nr01, nr23, ng01, ng23, nb01, nb23, dn01, dn23);
#pragma unroll 1
    for (int t = 0; t < 2; ++t)
        do_row<1, 0, 10>(win4, ty + 4 + t * 2, tx, scale, G01, G23,
                         nr01, nr23, ng01, ng23, nb01, nb23, dn01, dn23);
    do_row<0, 0, 10>(win4, ty + 5, tx, scale, G01, G23,
                     nr01, nr23, ng01, ng23, nb01, nb23, dn01, dn23);

    // epilogue: 4 consecutive pixels -> float4 stores per channel
    const int ox = bx0 + 4 * tx;
    const int oy = by0 + ty;
    const size_t obase = (size_t)b * 3 * HW + (size_t)oy * IMG_W + ox;

    const float i0 = __builtin_amdgcn_rcpf(dn01.x + 1e-8f);
    const float i1 = __builtin_amdgcn_rcpf(dn01.y + 1e-8f);
    const float i2 = __builtin_amdgcn_rcpf(dn23.x + 1e-8f);
    const float i3 = __builtin_amdgcn_rcpf(dn23.y + 1e-8f);

    float4 o;
    o.x = nr01.x * i0; o.y = nr01.y * i1; o.z = nr23.x * i2; o.w = nr23.y * i3;
    *reinterpret_cast<float4*>(&out[obase]) = o;
    o.x = ng01.x * i0; o.y = ng01.y * i1; o.z = ng23.x * i2; o.w = ng23.y * i3;
    *reinterpret_cast<float4*>(&out[obase + HW]) = o;
    o.x = nb01.x * i0; o.y = nb01.y * i1; o.z = nb23.x * i2; o.w = nb23.y * i3;
    *reinterpret_cast<float4*>(&out[obase + 2 * HW]) = o;
}

extern "C" void kernel_launch(void* const* d_in, const int* in_sizes, int n_in,
                              void* d_out, int out_size, void* d_ws, size_t ws_size,
                              hipStream_t stream) {
    const float* x    = (const float*)d_in[0];
    const float* lens = (const float*)d_in[1];
    float* out        = (float*)d_out;

    const int B = in_sizes[1];  // lens_effects has B elements

    dim3 block(16, 16, 1);
    dim3 grid(IMG_W / TSX, IMG_H / TSY, B);
    scatter_render_kernel<<<grid, block, 0, stream>>>(x, lens, out);
}

// Round 5
// 117.299 us; speedup vs baseline: 82.6882x; 82.6882x over previous
//
#include <hip/hip_runtime.h>

#define LENSZ 11
#define RAD   5
#define TSX   64            // tile width  (4 px per thread in x)
#define TSY   16            // tile height
#define WINX  (TSX + LENSZ - 1)   // 74
#define WINY  (TSY + LENSZ - 1)   // 26
#define NI    19            // ceil(WINX/4)
#define WXP   76            // padded window width for staging (4*NI)
#define IMG_H 1024
#define IMG_W 1024
#define HW    (IMG_H * IMG_W)

// sigmoid(4*(sd-dd)) = 1/(1 + exp2(C4L2*(sd-dd))), C4L2 = -4*log2(e)
#define C4L2  (-5.770780163555854f)

typedef float v2f __attribute__((ext_vector_type(2)));

// c0 = 0.5 - dist(dy,dx), literal table (R3 lesson: iterative constexpr math
// does NOT fold outside constant-expression contexts -> ran 48 f64 Newton
// iterations per pair at runtime). n = dy^2+dx^2 takes 16 in-disk values.
// Out-of-disk (n > 30): -1e30 so clamp(coc+c0,0,1)==0 -> weight 0.
constexpr float C0V(int dy, int dx) {
    switch (dy * dy + dx * dx) {
        case 0:  return  0.5f;
        case 1:  return -0.5f;
        case 2:  return -0.914213562f;
        case 4:  return -1.5f;
        case 5:  return -1.736067977f;
        case 8:  return -2.328427125f;
        case 9:  return -2.5f;
        case 10: return -2.662277660f;
        case 13: return -3.105551275f;
        case 16: return -3.5f;
        case 17: return -3.623105626f;
        case 18: return -3.742640687f;
        case 20: return -3.972135955f;
        case 25: return -4.5f;
        case 26: return -4.599019514f;
        case 29: return -4.885164807f;
        default: return -1e30f;
    }
}

// One window row at runtime y-index `wy`, with compile-time |dy| and disk
// x-bounds. Dests j=0..3 processed as packed pairs {0,1},{2,3}.
template<int ADY, int XMN, int XMX>
__device__ __forceinline__ void do_row(
    const float4 (&w4)[4][WINY][NI], int wy, int tx, float scale,
    v2f G01, v2f G23,
    v2f& nr01, v2f& nr23, v2f& ng01, v2f& ng23,
    v2f& nb01, v2f& nb23, v2f& dn01, v2f& dn23)
{
#pragma unroll
    for (int kxp = XMN; kxp <= XMX + 3; ++kxp) {
        float4 s = w4[kxp & 3][wy][tx + (kxp >> 2)];
        const float sd  = s.w;
        const float coc = scale * fabsf(sd);
        const float Es  = __builtin_amdgcn_exp2f(fminf(C4L2 * sd, 63.f));
        const v2f Es2 = {Es, Es};
        const v2f coc2 = {coc, coc};
        const v2f sx2 = {s.x, s.x}, sy2 = {s.y, s.y}, sz2 = {s.z, s.z};

        if (kxp <= XMX + 1) {  // pair {j=0,1}: kx = kxp, kxp-1 (folds post-unroll)
            const v2f c0 = {C0V(ADY, kxp - RAD), C0V(ADY, kxp - 1 - RAD)};
            v2f t = coc2 + c0;                                    // pk_add
            v2f w0 = {fminf(fmaxf(t.x, 0.f), 1.f),
                      fminf(fmaxf(t.y, 0.f), 1.f)};               // med3 x2
            v2f f = Es2 * G01 + (v2f){1.f, 1.f};                  // pk_fma
            float r = __builtin_amdgcn_rcpf(f.x * f.y);
            v2f occ = {r * f.y, r * f.x};
            v2f w = w0 * occ;                                     // pk_mul
            nr01 = w * sx2 + nr01;                                // pk_fma
            ng01 = w * sy2 + ng01;
            nb01 = w * sz2 + nb01;
            dn01 = dn01 + w;                                      // pk_add
        }
        if (kxp >= XMN + 2) {  // pair {j=2,3}: kx = kxp-2, kxp-3
            const v2f c0 = {C0V(ADY, kxp - 2 - RAD), C0V(ADY, kxp - 3 - RAD)};
            v2f t = coc2 + c0;
            v2f w0 = {fminf(fmaxf(t.x, 0.f), 1.f),
                      fminf(fmaxf(t.y, 0.f), 1.f)};
            v2f f = Es2 * G23 + (v2f){1.f, 1.f};
            float r = __builtin_amdgcn_rcpf(f.x * f.y);
            v2f occ = {r * f.y, r * f.x};
            v2f w = w0 * occ;
            nr23 = w * sx2 + nr23;
            ng23 = w * sy2 + ng23;
            nb23 = w * sz2 + nb23;
            dn23 = dn23 + w;
        }
    }
}

__global__ __launch_bounds__(256) void scatter_render_kernel(
    const float* __restrict__ x,      // (B,4,H,W)
    const float* __restrict__ lens,   // (B,1)
    float* __restrict__ out)          // (B,3,H,W)
{
    // column-mod-4 interleaved window: element (wy, c) at win4[c&3][wy][c>>2]
    __shared__ float4 win4[4][WINY][NI];

    const int b   = blockIdx.z;
    const int bx0 = blockIdx.x * TSX;
    const int by0 = blockIdx.y * TSY;
    const int tx  = threadIdx.x;      // 0..15
    const int ty  = threadIdx.y;      // 0..15
    const int tid = ty * 16 + tx;

    const float scale = lens[b];
    const float* xb = x + (size_t)b * 4 * HW;

    // ---- stage window: coalesced global reads, bank-uniform LDS writes
    for (int idx = tid; idx < WINY * WXP; idx += 256) {
        int wy = idx / WXP;
        int c  = idx - wy * WXP;
        int cc = min(c, WINX - 1);               // clamp padding columns
        int gy = by0 - RAD + wy; gy = min(max(gy, 0), IMG_H - 1);
        int gx = bx0 - RAD + cc; gx = min(max(gx, 0), IMG_W - 1);
        int base = gy * IMG_W + gx;
        float4 v;
        v.x = xb[base];
        v.y = xb[base + HW];
        v.z = xb[base + 2 * HW];
        v.w = xb[base + 3 * HW];
        win4[c & 3][wy][c >> 2] = v;
    }
    __syncthreads();

    // per-dest occlusion gate: G_j = exp2(min(-C4L2 * dd_j, 63))
    float G[4];
#pragma unroll
    for (int j = 0; j < 4; ++j) {
        const int cc = 4 * tx + j + RAD;
        float dd = win4[cc & 3][ty + RAD][cc >> 2].w;
        G[j] = __builtin_amdgcn_exp2f(fminf(-C4L2 * dd, 63.f));
    }
    const v2f G01 = {G[0], G[1]}, G23 = {G[2], G[3]};

    v2f nr01 = {0,0}, nr23 = {0,0}, ng01 = {0,0}, ng23 = {0,0};
    v2f nb01 = {0,0}, nb23 = {0,0}, dn01 = {0,0}, dn23 = {0,0};

    // mirrored row pairs share |dy| -> c0 fully compile-time; runtime 2-trip
    // loops keep live ranges bounded (R1's full unroll spilled).
#pragma unroll 1
    for (int t = 0; t < 2; ++t)
        do_row<5, 3, 7>(win4, ty + t * 10, tx, scale, G01, G23,
                        nr01, nr23, ng01, ng23, nb01, nb23, dn01, dn23);
#pragma unroll 1
    for (int t = 0; t < 2; ++t)
        do_row<4, 2, 8>(win4, ty + 1 + t * 8, tx, scale, G01, G23,
                        nr01, nr23, ng01, ng23, nb01, nb23, dn01, dn23);
#pragma unroll 1
    for (int t = 0; t < 2; ++t)
        do_row<3, 1, 9>(win4, ty + 2 + t * 6, tx, scale, G01, G23,
                        nr01, nr23, ng01, ng23, nb01, nb23, dn01, dn23);
#pragma unroll 1
    for (int t = 0; t < 2; ++t)
        do_row<2, 0, 10>(win4, ty + 3 + t * 4, tx, scale, G01, G23,
                         nr01, nr23, ng01, ng23, nb01, nb23, dn01, dn23);
#pragma unroll 1
    for (int t = 0; t < 2; ++t)
        do_row<1, 0, 10>(win4, ty + 4 + t * 2, tx, scale, G01, G23,
                         nr01, nr23, ng01, ng23, nb01, nb23, dn01, dn23);
    do_row<0, 0, 10>(win4, ty + 5, tx, scale, G01, G23,
                     nr01, nr23, ng01, ng23, nb01, nb23, dn01, dn23);

    // epilogue: 4 consecutive pixels -> float4 stores per channel
    const int ox = bx0 + 4 * tx;
    const int oy = by0 + ty;
    const size_t obase = (size_t)b * 3 * HW + (size_t)oy * IMG_W + ox;

    const float i0 = __builtin_amdgcn_rcpf(dn01.x + 1e-8f);
    const float i1 = __builtin_amdgcn_rcpf(dn01.y + 1e-8f);
    const float i2 = __builtin_amdgcn_rcpf(dn23.x + 1e-8f);
    const float i3 = __builtin_amdgcn_rcpf(dn23.y + 1e-8f);

    float4 o;
    o.x = nr01.x * i0; o.y = nr01.y * i1; o.z = nr23.x * i2; o.w = nr23.y * i3;
    *reinterpret_cast<float4*>(&out[obase]) = o;
    o.x = ng01.x * i0; o.y = ng01.y * i1; o.z = ng23.x * i2; o.w = ng23.y * i3;
    *reinterpret_cast<float4*>(&out[obase + HW]) = o;
    o.x = nb01.x * i0; o.y = nb01.y * i1; o.z = nb23.x * i2; o.w = nb23.y * i3;
    *reinterpret_cast<float4*>(&out[obase + 2 * HW]) = o;
}

extern "C" void kernel_launch(void* const* d_in, const int* in_sizes, int n_in,
                              void* d_out, int out_size, void* d_ws, size_t ws_size,
                              hipStream_t stream) {
    const float* x    = (const float*)d_in[0];
    const float* lens = (const float*)d_in[1];
    float* out        = (float*)d_out;

    const int B = in_sizes[1];  // lens_effects has B elements

    dim3 block(16, 16, 1);
    dim3 grid(IMG_W / TSX, IMG_H / TSY, B);
    scatter_render_kernel<<<grid, block, 0, stream>>>(x, lens, out);
}